// Round 3
// baseline (3409.397 us; speedup 1.0000x reference)
//
#include <hip/hip_runtime.h>

// ---------------------------------------------------------------------------
// RWKV-7 MoE FFN, MI355X (gfx950). Dense-expert bf16 MFMA implementation,
// M-chunked so scratch fits an unknown ws_size (floor ~83 MB).
// Router computed in f32 from raw inputs (bf16 scores flipped top-2 picks).
// Shapes fixed by setup_inputs(): B=4 T=2048 C=2048 H=8192 R=64 E=4, topk=2.
// ---------------------------------------------------------------------------

#define DEV_INLINE __device__ __forceinline__

typedef __attribute__((ext_vector_type(8))) short bf16x8;
typedef __attribute__((ext_vector_type(4))) float f32x4;

DEV_INLINE unsigned short f2bf(float f) {
  union { float f; unsigned int u; } v; v.f = f;
  unsigned int u = v.u;
  unsigned int r = (u + 0x7FFFu + ((u >> 16) & 1u)) >> 16;  // RTNE
  return (unsigned short)r;
}
DEV_INLINE float bf2f(unsigned short s) {
  union { unsigned int u; float f; } v; v.u = ((unsigned int)s) << 16;
  return v.f;
}

// ---------------------------------------------------------------------------
// prep (chunked): h_c[i] for global tokens n0..n0+MC-1:
//   h = x + (shift(x) - x) * x_k   -> bf16 [MC][C]
// one thread = one float4 (4 channels). C=2048 -> C4=512.
// ---------------------------------------------------------------------------
__global__ __launch_bounds__(256) void prep_kernel(
    const float* __restrict__ x, const float* __restrict__ x_prev,
    const float* __restrict__ x_k, unsigned short* __restrict__ h, int n0) {
  const int idx = blockIdx.x * 256 + threadIdx.x;   // local float4 index
  const int c4 = idx & 511;                         // C/4 = 512
  const int gn = n0 + (idx >> 9);                   // global token
  const int t  = gn & 2047;                         // T = 2048
  const int b  = gn >> 11;
  const float4 cur = ((const float4*)x)[(size_t)gn * 512 + c4];
  const float4 prv = (t == 0) ? ((const float4*)x_prev)[(b << 9) + c4]
                              : ((const float4*)x)[(size_t)gn * 512 - 512 + c4];
  const float4 k = ((const float4*)x_k)[c4];
  float hx = cur.x + (prv.x - cur.x) * k.x;
  float hy = cur.y + (prv.y - cur.y) * k.y;
  float hz = cur.z + (prv.z - cur.z) * k.z;
  float hw = cur.w + (prv.w - cur.w) * k.w;
  uint2 o;
  o.x = (unsigned int)f2bf(hx) | ((unsigned int)f2bf(hy) << 16);
  o.y = (unsigned int)f2bf(hz) | ((unsigned int)f2bf(hw) << 16);
  ((uint2*)h)[idx] = o;
}

// x_last = x[:, T-1, :]  (B=4, C=2048 -> 2048 float4s)
__global__ __launch_bounds__(256) void xlast_kernel(
    const float* __restrict__ x, float* __restrict__ x_last) {
  const int i = blockIdx.x * 256 + threadIdx.x;  // [0, 2048)
  const int b = i >> 9, c4 = i & 511;
  ((float4*)x_last)[i] =
      ((const float4*)x)[((size_t)b * 2048 + 2047) * 512 + c4];
}

// ---------------------------------------------------------------------------
// transpose + cast f32 -> bf16:  out[c][r] = in[r][c].  block (32,8), LDS tile.
// ---------------------------------------------------------------------------
__global__ __launch_bounds__(256) void transpose_cast(
    const float* __restrict__ in, unsigned short* __restrict__ outp,
    int rows, int cols) {
  __shared__ float tile[32][33];
  const int bx = blockIdx.x * 32, by = blockIdx.y * 32;
  const int tx = threadIdx.x, ty = threadIdx.y;
#pragma unroll
  for (int k = 0; k < 4; ++k)
    tile[ty + k * 8][tx] = in[(size_t)(by + ty + k * 8) * cols + bx + tx];
  __syncthreads();
#pragma unroll
  for (int k = 0; k < 4; ++k)
    outp[(size_t)(bx + ty + k * 8) * rows + by + tx] = f2bf(tile[tx][ty + k * 8]);
}

// plain cast f32 -> bf16, one float4 per thread
__global__ __launch_bounds__(256) void cast_bf16(
    const float* __restrict__ in, unsigned short* __restrict__ outp, int n4) {
  const int i = blockIdx.x * 256 + threadIdx.x;
  if (i >= n4) return;
  const float4 v = ((const float4*)in)[i];
  uint2 o;
  o.x = (unsigned int)f2bf(v.x) | ((unsigned int)f2bf(v.y) << 16);
  o.y = (unsigned int)f2bf(v.z) | ((unsigned int)f2bf(v.w) << 16);
  ((uint2*)outp)[i] = o;
}

// ---------------------------------------------------------------------------
// router (chunked, FULL f32 from raw inputs — bf16 h flips top-2 near-ties):
// h_f32 = x + (shift(x)-x)*x_k; scores_e = h.Router[e-1] (e=1..3), s0 = 0;
// top-2 softmax. one wave per token; gating_c: [MC][4] f32.
// ---------------------------------------------------------------------------
__global__ __launch_bounds__(256) void router_kernel(
    const float* __restrict__ x, const float* __restrict__ x_prev,
    const float* __restrict__ x_k, const float* __restrict__ Rt,
    float* __restrict__ gating, int n0) {
  const int lane = threadIdx.x & 63, wid = threadIdx.x >> 6;
  const int nl = blockIdx.x * 4 + wid;  // local token
  const int gn = n0 + nl;
  const int t = gn & 2047, b = gn >> 11;
  const float* cur = x + (size_t)gn * 2048;
  const float* prv = (t == 0) ? x_prev + (size_t)b * 2048 : cur - 2048;
  float hv[32];
#pragma unroll
  for (int j = 0; j < 32; ++j) {
    const int i = j * 64 + lane;
    const float xc = cur[i];
    hv[j] = xc + (prv[i] - xc) * x_k[i];
  }
  float s[4];
  s[0] = 0.f;
  for (int e = 1; e < 4; ++e) {
    const float* rrow = Rt + (size_t)(e - 1) * 2048;
    float a = 0.f;
#pragma unroll
    for (int j = 0; j < 32; ++j) a += hv[j] * rrow[j * 64 + lane];
#pragma unroll
    for (int d = 32; d >= 1; d >>= 1) a += __shfl_xor(a, d, 64);
    s[e] = a;
  }
  if (lane == 0) {
    int i1 = 0; float v1 = s[0];
    for (int e = 1; e < 4; ++e) if (s[e] > v1) { v1 = s[e]; i1 = e; }
    int i2 = -1; float v2 = -1e30f;
    for (int e = 0; e < 4; ++e) if (e != i1 && s[e] > v2) { v2 = s[e]; i2 = e; }
    const float ex = expf(v2 - v1);
    const float g1 = 1.f / (1.f + ex), g2 = ex / (1.f + ex);
    float ge[4] = {0.f, 0.f, 0.f, 0.f};
    ge[i1] = g1; ge[i2] = g2;
    float4 o; o.x = ge[0]; o.y = ge[1]; o.z = ge[2]; o.w = ge[3];
    ((float4*)gating)[nl] = o;
  }
}

// ---------------------------------------------------------------------------
// Generic B^T GEMM:  C[M][Nc] (epilogue-dependent) = A[M][K]bf16 x Bt[Nc][K]bf16
// 128 x BN x BK=64 tile, mfma_f32_16x16x32_bf16, global_load_lds width-16
// staging with XOR-swizzled LDS (pre-swizzled global source, m173/#21),
// m97 2-barrier loop structure.
// Epilogues: 0 = store bf16; 1 = k_e = relu(aux + 2*acc)^2 bf16;
//            2 = d_out f32: init ? g*acc : += g*acc, g = gate[row][e]*scale.
// ---------------------------------------------------------------------------
enum { EPI_BF16 = 0, EPI_KE = 1, EPI_GATE = 2 };

template <int BN, int NW, int EPI>
__global__ __launch_bounds__(64 * NW) void gemm_bt(
    const unsigned short* __restrict__ A, int lda,
    const unsigned short* __restrict__ B, int ldb,
    void* __restrict__ Cp, int ldc,
    const unsigned short* __restrict__ aux, int ldaux,
    const float* __restrict__ gate, int eidx, float scale, int initC, int K) {
  constexpr int BM = 128, BK = 64;
  constexpr int WN = (BN >= 128) ? 2 : 1;
  constexpr int WM = NW / WN;
  constexpr int WTM = BM / WM;          // wave tile rows
  constexpr int WTN = BN / WN;          // wave tile cols
  constexpr int FM = WTM / 16, FN = WTN / 16;
  constexpr int THREADS = 64 * NW;
  constexpr int ACH = BM * BK / 8;      // 16B chunks in A tile
  constexpr int BCH = BN * BK / 8;

  __shared__ alignas(16) char smem[(BM + BN) * BK * 2];
  char* As = smem;
  char* Bs = smem + BM * BK * 2;

  const int tid = threadIdx.x;
  const int lane = tid & 63;
  const int wid = tid >> 6;
  const int wr = wid / WN, wc = wid % WN;
  const int m0 = blockIdx.y * BM;
  const int n0 = blockIdx.x * BN;

  f32x4 acc[FM][FN] = {};

  for (int kt = 0; kt < K; kt += BK) {
    __syncthreads();  // previous tile's reads done before overwrite
#pragma unroll
    for (int q0 = 0; q0 < ACH; q0 += THREADS) {
      const int q = q0 + tid;
      const int row = q >> 3, w = q & 7;
      const int g = w ^ (row & 7);      // pre-swizzled global source (m173)
      const unsigned short* src = A + (size_t)(m0 + row) * lda + kt + g * 8;
      __builtin_amdgcn_global_load_lds(
          (const __attribute__((address_space(1))) void*)src,
          (__attribute__((address_space(3))) void*)(As + q * 16), 16, 0, 0);
    }
#pragma unroll
    for (int q0 = 0; q0 < BCH; q0 += THREADS) {
      const int q = q0 + tid;
      const int row = q >> 3, w = q & 7;
      const int g = w ^ (row & 7);
      const unsigned short* src = B + (size_t)(n0 + row) * ldb + kt + g * 8;
      __builtin_amdgcn_global_load_lds(
          (const __attribute__((address_space(1))) void*)src,
          (__attribute__((address_space(3))) void*)(Bs + q * 16), 16, 0, 0);
    }
    asm volatile("s_waitcnt vmcnt(0)" ::: "memory");
    __syncthreads();

#pragma unroll
    for (int ks = 0; ks < BK / 32; ++ks) {
      bf16x8 af[FM], bfr[FN];
#pragma unroll
      for (int m = 0; m < FM; ++m) {
        const int row = wr * WTM + m * 16 + (lane & 15);
        const int kb = (ks * 64 + ((lane >> 4) * 16)) ^ ((row & 7) << 4);
        af[m] = *(const bf16x8*)(As + row * (BK * 2) + kb);
      }
#pragma unroll
      for (int n = 0; n < FN; ++n) {
        const int row = wc * WTN + n * 16 + (lane & 15);
        const int kb = (ks * 64 + ((lane >> 4) * 16)) ^ ((row & 7) << 4);
        bfr[n] = *(const bf16x8*)(Bs + row * (BK * 2) + kb);
      }
#pragma unroll
      for (int m = 0; m < FM; ++m)
#pragma unroll
        for (int n = 0; n < FN; ++n)
          acc[m][n] = __builtin_amdgcn_mfma_f32_16x16x32_bf16(
              af[m], bfr[n], acc[m][n], 0, 0, 0);
    }
  }

  // epilogue: C/D layout col = lane&15, row = (lane>>4)*4 + j  [m89/m91]
  const int cc = lane & 15;
  const int cr0 = (lane >> 4) * 4;
#pragma unroll
  for (int m = 0; m < FM; ++m) {
#pragma unroll
    for (int n = 0; n < FN; ++n) {
#pragma unroll
      for (int j = 0; j < 4; ++j) {
        const int grow = m0 + wr * WTM + m * 16 + cr0 + j;
        const int gcol = n0 + wc * WTN + n * 16 + cc;
        const float v = acc[m][n][j];
        if constexpr (EPI == EPI_BF16) {
          ((unsigned short*)Cp)[(size_t)grow * ldc + gcol] = f2bf(v);
        } else if constexpr (EPI == EPI_KE) {
          const float ksv = bf2f(aux[(size_t)grow * ldaux + gcol]);
          float r = ksv + 2.0f * v;      // LORA_SCALING = 2
          r = r > 0.f ? r : 0.f;
          ((unsigned short*)Cp)[(size_t)grow * ldc + gcol] = f2bf(r * r);
        } else {
          const float g = gate[grow * 4 + eidx] * scale;
          float* o = (float*)Cp + (size_t)grow * ldc + gcol;
          *o = initC ? (g * v) : (*o + g * v);
        }
      }
    }
  }
}

// ---------------------------------------------------------------------------
extern "C" void kernel_launch(void* const* d_in, const int* in_sizes, int n_in,
                              void* d_out, int out_size, void* d_ws,
                              size_t ws_size, hipStream_t stream) {
  (void)in_sizes; (void)n_in; (void)out_size;
  const float* x      = (const float*)d_in[0];
  const float* x_prev = (const float*)d_in[1];
  const float* x_k    = (const float*)d_in[2];
  const float* Router = (const float*)d_in[3];
  const float* K_ref  = (const float*)d_in[4];
  const float* V_ref  = (const float*)d_in[5];
  const float* Ka     = (const float*)d_in[6];
  const float* Kb     = (const float*)d_in[7];
  const float* Va     = (const float*)d_in[8];
  const float* Vb     = (const float*)d_in[9];

  constexpr int Bb = 4, T = 2048, C = 2048, H = 8192, R = 64, E = 4;
  constexpr int M = Bb * T;  // 8192 tokens

  // ---- workspace layout: persistent weights + per-chunk token buffers ----
  const size_t PAD = 255;
  auto rnd = [&](size_t b) { return (b + PAD) & ~PAD; };
  const size_t persist = rnd((size_t)H * C * 2) + rnd((size_t)C * H * 2)
                       + rnd((size_t)E * R * C * 2) + rnd((size_t)E * H * R * 2)
                       + rnd((size_t)E * R * H * 2) + rnd((size_t)E * C * R * 2);

  // pick largest chunk MC (multiple of 128, divides M) whose buffers fit
  int MC = 0;
  for (int cand = M; cand >= 128; cand >>= 1) {
    const size_t per = rnd((size_t)cand * C * 2)        // h_c
                     + rnd((size_t)cand * E * 4)        // gating
                     + rnd((size_t)cand * E * R * 2)    // lora
                     + rnd((size_t)cand * H * 2)        // kshared
                     + rnd((size_t)cand * H * 2)        // k_e
                     + rnd((size_t)cand * R * 2);       // vat
    if (persist + per <= ws_size) { MC = cand; break; }
  }
  if (MC == 0) return;  // ws hopelessly small; output stays zero (signals us)

  char* ws = (char*)d_ws;
  size_t off = 0;
  auto alloc = [&](size_t bytes) -> char* {
    char* p = ws + off; off += rnd(bytes); return p;
  };
  unsigned short* Kt   = (unsigned short*)alloc((size_t)H * C * 2);
  unsigned short* Vt   = (unsigned short*)alloc((size_t)C * H * 2);
  unsigned short* KaB  = (unsigned short*)alloc((size_t)E * R * C * 2);
  unsigned short* KbB  = (unsigned short*)alloc((size_t)E * H * R * 2);
  unsigned short* VaB  = (unsigned short*)alloc((size_t)E * R * H * 2);
  unsigned short* VbB  = (unsigned short*)alloc((size_t)E * C * R * 2);
  unsigned short* h_c  = (unsigned short*)alloc((size_t)MC * C * 2);
  float*          gat  = (float*)alloc((size_t)MC * E * 4);
  unsigned short* lora = (unsigned short*)alloc((size_t)MC * E * R * 2);
  unsigned short* ksh  = (unsigned short*)alloc((size_t)MC * H * 2);
  unsigned short* k_e  = (unsigned short*)alloc((size_t)MC * H * 2);
  unsigned short* vat  = (unsigned short*)alloc((size_t)MC * R * 2);

  float* out    = (float*)d_out;
  float* x_last = out + (size_t)M * C;

  // ---- one-time: weights -> bf16 (K_ref/V_ref transposed to B^T) ----
  transpose_cast<<<dim3(H / 32, C / 32), dim3(32, 8), 0, stream>>>(K_ref, Kt, C, H);
  transpose_cast<<<dim3(C / 32, H / 32), dim3(32, 8), 0, stream>>>(V_ref, Vt, H, C);
  cast_bf16<<<(E * R * C / 4 + 255) / 256, 256, 0, stream>>>(Ka, KaB, E * R * C / 4);
  cast_bf16<<<(E * H * R / 4 + 255) / 256, 256, 0, stream>>>(Kb, KbB, E * H * R / 4);
  cast_bf16<<<(E * R * H / 4 + 255) / 256, 256, 0, stream>>>(Va, VaB, E * R * H / 4);
  cast_bf16<<<(E * C * R / 4 + 255) / 256, 256, 0, stream>>>(Vb, VbB, E * C * R / 4);
  xlast_kernel<<<Bb * C / 4 / 256, 256, 0, stream>>>(x, x_last);

  // ---- per-chunk pipeline ----
  for (int c0 = 0; c0 < M; c0 += MC) {
    // token shift -> h_c (bf16)
    prep_kernel<<<MC * C / 4 / 256, 256, 0, stream>>>(x, x_prev, x_k, h_c, c0);
    // router (f32 end-to-end) -> gat [MC][4]
    router_kernel<<<MC / 4, 256, 0, stream>>>(x, x_prev, x_k, Router, gat, c0);
    // kshared = h @ K_ref   [MC x H], K=C
    gemm_bt<128, 4, EPI_BF16><<<dim3(H / 128, MC / 128), 256, 0, stream>>>(
        h_c, C, Kt, C, ksh, H, nullptr, 0, nullptr, 0, 0.f, 0, C);
    // lora_all = h @ KaAll^T  [MC x E*R], K=C
    gemm_bt<128, 4, EPI_BF16><<<dim3(E * R / 128, MC / 128), 256, 0, stream>>>(
        h_c, C, KaB, C, lora, E * R, nullptr, 0, nullptr, 0, 0.f, 0, C);

    for (int e = 0; e < E; ++e) {
      // k_e = relu(kshared + 2 * lora_e @ Kb[e]^T)^2   [MC x H], K=R
      gemm_bt<128, 4, EPI_KE><<<dim3(H / 128, MC / 128), 256, 0, stream>>>(
          lora + e * R, E * R, KbB + (size_t)e * H * R, R, k_e, H,
          ksh, H, nullptr, 0, 0.f, 0, R);
      // vat = k_e @ Va[e]^T   [MC x R], K=H
      gemm_bt<64, 2, EPI_BF16><<<dim3(R / 64, MC / 128), 128, 0, stream>>>(
          k_e, H, VaB + (size_t)e * R * H, H, vat, R,
          nullptr, 0, nullptr, 0, 0.f, 0, H);
      // out (+)= g_e * (k_e @ V_ref)   [MC x C], K=H ; init on e==0
      gemm_bt<128, 4, EPI_GATE><<<dim3(C / 128, MC / 128), 256, 0, stream>>>(
          k_e, H, Vt, H, out + (size_t)c0 * C, C, nullptr, 0, gat, e, 1.0f,
          (e == 0) ? 1 : 0, H);
      // out += 2 * g_e * (vat @ Vb[e]^T)   [MC x C], K=R
      gemm_bt<128, 4, EPI_GATE><<<dim3(C / 128, MC / 128), 256, 0, stream>>>(
          vat, R, VbB + (size_t)e * C * R, R, out + (size_t)c0 * C, C,
          nullptr, 0, gat, e, 2.0f, 0, R);
    }
  }
}

// Round 4
// 2653.144 us; speedup vs baseline: 1.2850x; 1.2850x over previous
//
#include <hip/hip_runtime.h>

// ---------------------------------------------------------------------------
// RWKV-7 MoE FFN, MI355X (gfx950). bf16 MFMA + top-2 SPARSE expert dispatch.
// Slot-lists: slot0 = primary expert of each token, slot1 = secondary.
// Each slot list = MC rows (fixed), expert-sorted, segments padded to 128.
// Shapes fixed: B=4 T=2048 C=2048 H=8192 R=64 E=4, topk=2.
// ---------------------------------------------------------------------------

#define DEV_INLINE __device__ __forceinline__

typedef __attribute__((ext_vector_type(8))) short bf16x8;
typedef __attribute__((ext_vector_type(4))) float f32x4;

DEV_INLINE unsigned short f2bf(float f) {
  union { float f; unsigned int u; } v; v.f = f;
  unsigned int u = v.u;
  unsigned int r = (u + 0x7FFFu + ((u >> 16) & 1u)) >> 16;  // RTNE
  return (unsigned short)r;
}
DEV_INLINE float bf2f(unsigned short s) {
  union { unsigned int u; float f; } v; v.u = ((unsigned int)s) << 16;
  return v.f;
}

// tbl layout (ints): [0:8) hist[2][4], [8:16) fill[2][4], [16:26) base[2][5],
// [32:32+2*MB) blocktab[2][MB], [32+2*MB : 32+2*MB+2*MB*128) tok[2][MB*128]

// ---------------------------------------------------------------------------
__global__ __launch_bounds__(256) void prep_kernel(
    const float* __restrict__ x, const float* __restrict__ x_prev,
    const float* __restrict__ x_k, unsigned short* __restrict__ h, int n0) {
  const int idx = blockIdx.x * 256 + threadIdx.x;   // local float4 index
  const int c4 = idx & 511;                         // C/4 = 512
  const int gn = n0 + (idx >> 9);                   // global token
  const int t  = gn & 2047;                         // T = 2048
  const int b  = gn >> 11;
  const float4 cur = ((const float4*)x)[(size_t)gn * 512 + c4];
  const float4 prv = (t == 0) ? ((const float4*)x_prev)[(b << 9) + c4]
                              : ((const float4*)x)[(size_t)gn * 512 - 512 + c4];
  const float4 k = ((const float4*)x_k)[c4];
  float hx = cur.x + (prv.x - cur.x) * k.x;
  float hy = cur.y + (prv.y - cur.y) * k.y;
  float hz = cur.z + (prv.z - cur.z) * k.z;
  float hw = cur.w + (prv.w - cur.w) * k.w;
  uint2 o;
  o.x = (unsigned int)f2bf(hx) | ((unsigned int)f2bf(hy) << 16);
  o.y = (unsigned int)f2bf(hz) | ((unsigned int)f2bf(hw) << 16);
  ((uint2*)h)[idx] = o;
}

__global__ __launch_bounds__(256) void xlast_kernel(
    const float* __restrict__ x, float* __restrict__ x_last) {
  const int i = blockIdx.x * 256 + threadIdx.x;  // [0, 2048)
  const int b = i >> 9, c4 = i & 511;
  ((float4*)x_last)[i] =
      ((const float4*)x)[((size_t)b * 2048 + 2047) * 512 + c4];
}

__global__ __launch_bounds__(256) void transpose_cast(
    const float* __restrict__ in, unsigned short* __restrict__ outp,
    int rows, int cols) {
  __shared__ float tile[32][33];
  const int bx = blockIdx.x * 32, by = blockIdx.y * 32;
  const int tx = threadIdx.x, ty = threadIdx.y;
#pragma unroll
  for (int k = 0; k < 4; ++k)
    tile[ty + k * 8][tx] = in[(size_t)(by + ty + k * 8) * cols + bx + tx];
  __syncthreads();
#pragma unroll
  for (int k = 0; k < 4; ++k)
    outp[(size_t)(bx + ty + k * 8) * rows + by + tx] = f2bf(tile[tx][ty + k * 8]);
}

__global__ __launch_bounds__(256) void cast_bf16(
    const float* __restrict__ in, unsigned short* __restrict__ outp, int n4) {
  const int i = blockIdx.x * 256 + threadIdx.x;
  if (i >= n4) return;
  const float4 v = ((const float4*)in)[i];
  uint2 o;
  o.x = (unsigned int)f2bf(v.x) | ((unsigned int)f2bf(v.y) << 16);
  o.y = (unsigned int)f2bf(v.z) | ((unsigned int)f2bf(v.w) << 16);
  ((uint2*)outp)[i] = o;
}

// ---------------------------------------------------------------------------
// router (f32 end-to-end from raw inputs): per token top-2 -> expert ids,
// gate values, and per-(slot,expert) histogram.
// ---------------------------------------------------------------------------
__global__ __launch_bounds__(256) void router_kernel(
    const float* __restrict__ x, const float* __restrict__ x_prev,
    const float* __restrict__ x_k, const float* __restrict__ Rt,
    int* __restrict__ tbl, int* __restrict__ etok,
    float* __restrict__ gate_tok, int MC, int n0) {
  const int lane = threadIdx.x & 63, wid = threadIdx.x >> 6;
  const int nl = blockIdx.x * 4 + wid;  // local token
  const int gn = n0 + nl;
  const int t = gn & 2047, b = gn >> 11;
  const float* cur = x + (size_t)gn * 2048;
  const float* prv = (t == 0) ? x_prev + (size_t)b * 2048 : cur - 2048;
  float hv[32];
#pragma unroll
  for (int j = 0; j < 32; ++j) {
    const int i = j * 64 + lane;
    const float xc = cur[i];
    hv[j] = xc + (prv[i] - xc) * x_k[i];
  }
  float s[4];
  s[0] = 0.f;
  for (int e = 1; e < 4; ++e) {
    const float* rrow = Rt + (size_t)(e - 1) * 2048;
    float a = 0.f;
#pragma unroll
    for (int j = 0; j < 32; ++j) a += hv[j] * rrow[j * 64 + lane];
#pragma unroll
    for (int d = 32; d >= 1; d >>= 1) a += __shfl_xor(a, d, 64);
    s[e] = a;
  }
  if (lane == 0) {
    int i1 = 0; float v1 = s[0];
    for (int e = 1; e < 4; ++e) if (s[e] > v1) { v1 = s[e]; i1 = e; }
    int i2 = -1; float v2 = -1e30f;
    for (int e = 0; e < 4; ++e) if (e != i1 && s[e] > v2) { v2 = s[e]; i2 = e; }
    const float ex = expf(v2 - v1);
    const float g1 = 1.f / (1.f + ex), g2 = ex / (1.f + ex);
    etok[nl] = i1;          etok[MC + nl] = i2;
    gate_tok[nl] = g1;      gate_tok[MC + nl] = g2;
    atomicAdd(&tbl[i1], 1); atomicAdd(&tbl[4 + i2], 1);
  }
}

__global__ void zero_hist(int* tbl) {
  if (threadIdx.x < 8) tbl[threadIdx.x] = 0;
}

// 1 block, 128 threads: bases (128-padded prefix), blocktab, tok=-1, fill=0
__global__ __launch_bounds__(128) void seg_build(int* __restrict__ tbl, int MB) {
  const int tid = threadIdx.x;
  __shared__ int sbase[2][5];
  if (tid == 0) {
    for (int k = 0; k < 2; ++k) {
      int b = 0; sbase[k][0] = 0;
      for (int e = 0; e < 4; ++e) {
        b += ((tbl[k * 4 + e] + 127) >> 7) << 7;
        sbase[k][e + 1] = b;
      }
      for (int e = 0; e < 5; ++e) tbl[16 + k * 5 + e] = sbase[k][e];
    }
    for (int i = 0; i < 8; ++i) tbl[8 + i] = 0;
  }
  __syncthreads();
  int* bt = tbl + 32;
  for (int i = tid; i < 2 * MB; i += 128) {
    const int k = i / MB, row = (i % MB) * 128;
    int e = -1;
    for (int q = 0; q < 4; ++q)
      if (row >= sbase[k][q] && row < sbase[k][q + 1]) e = q;
    bt[i] = e;
  }
  int* tok = tbl + 32 + 2 * MB;
  for (int i = tid; i < 2 * MB * 128; i += 128) tok[i] = -1;
}

__global__ __launch_bounds__(256) void scatter_build(
    int* __restrict__ tbl, const int* __restrict__ etok, int MC, int MB) {
  const int t = blockIdx.x * 256 + threadIdx.x;
  if (t >= MC) return;
  int* tok = tbl + 32 + 2 * MB;
#pragma unroll
  for (int k = 0; k < 2; ++k) {
    const int e = etok[k * MC + t];
    const int r = atomicAdd(&tbl[8 + k * 4 + e], 1);
    tok[k * MB * 128 + tbl[16 + k * 5 + e] + r] = t;
  }
}

// ---------------------------------------------------------------------------
// Generic B^T GEMM with optional expert segmentation / row gather / scatter.
// 128 x BN x BK=64 tile, mfma_f32_16x16x32_bf16, global_load_lds width-16,
// XOR-swizzled LDS (pre-swizzled global source), m97 2-barrier loop.
// blocktab: per-m-block expert id (or -1 -> early-out); null = dense.
// arowmap:  A-row gather list (and aux row for EPI_KE); null = identity.
// crowmap:  epilogue row scatter (EPI_GATE), -1 rows skipped; null = identity.
// ---------------------------------------------------------------------------
enum { EPI_BF16 = 0, EPI_KE = 1, EPI_GATE = 2 };

template <int BN, int NW, int EPI>
__global__ __launch_bounds__(64 * NW) void gemm_bt(
    const unsigned short* __restrict__ A, int lda, long long strideA,
    const unsigned short* __restrict__ B, int ldb, long long strideB,
    void* __restrict__ Cp, int ldc,
    const unsigned short* __restrict__ aux, int ldaux,
    const float* __restrict__ gate, float scale, int initC,
    const int* __restrict__ blocktab, const int* __restrict__ arowmap,
    const int* __restrict__ crowmap, int K) {
  constexpr int BM = 128, BK = 64;
  constexpr int WN = (BN >= 128) ? 2 : 1;
  constexpr int WM = NW / WN;
  constexpr int WTM = BM / WM;
  constexpr int WTN = BN / WN;
  constexpr int FM = WTM / 16, FN = WTN / 16;
  constexpr int THREADS = 64 * NW;
  constexpr int ACH = BM * BK / 8;
  constexpr int BCH = BN * BK / 8;

  int e = 0;
  if (blocktab) { e = blocktab[blockIdx.y]; if (e < 0) return; }

  __shared__ alignas(16) char smem[(BM + BN) * BK * 2];
  char* As = smem;
  char* Bs = smem + BM * BK * 2;

  const unsigned short* Ae = A + (size_t)e * strideA;
  const unsigned short* Be = B + (size_t)e * strideB;

  const int tid = threadIdx.x;
  const int lane = tid & 63;
  const int wid = tid >> 6;
  const int wr = wid / WN, wc = wid % WN;
  const int m0 = blockIdx.y * BM;
  const int n0 = blockIdx.x * BN;

  // cache this thread's A-row gather targets (fixed across K)
  int arow[ACH / THREADS];
#pragma unroll
  for (int i = 0; i < ACH / THREADS; ++i) {
    const int row = (i * THREADS + tid) >> 3;
    int r = m0 + row;
    if (arowmap) { r = arowmap[r]; if (r < 0) r = 0; }
    arow[i] = r;
  }

  f32x4 acc[FM][FN] = {};

  for (int kt = 0; kt < K; kt += BK) {
    __syncthreads();
#pragma unroll
    for (int i = 0; i < ACH / THREADS; ++i) {
      const int q = i * THREADS + tid;
      const int row = q >> 3, w = q & 7;
      const int g = w ^ (row & 7);
      const unsigned short* src = Ae + (size_t)arow[i] * lda + kt + g * 8;
      __builtin_amdgcn_global_load_lds(
          (const __attribute__((address_space(1))) void*)src,
          (__attribute__((address_space(3))) void*)(As + q * 16), 16, 0, 0);
    }
#pragma unroll
    for (int i = 0; i < BCH / THREADS; ++i) {
      const int q = i * THREADS + tid;
      const int row = q >> 3, w = q & 7;
      const int g = w ^ (row & 7);
      const unsigned short* src = Be + (size_t)(n0 + row) * ldb + kt + g * 8;
      __builtin_amdgcn_global_load_lds(
          (const __attribute__((address_space(1))) void*)src,
          (__attribute__((address_space(3))) void*)(Bs + q * 16), 16, 0, 0);
    }
    asm volatile("s_waitcnt vmcnt(0)" ::: "memory");
    __syncthreads();

#pragma unroll
    for (int ks = 0; ks < BK / 32; ++ks) {
      bf16x8 af[FM], bfr[FN];
#pragma unroll
      for (int m = 0; m < FM; ++m) {
        const int row = wr * WTM + m * 16 + (lane & 15);
        const int kb = (ks * 64 + ((lane >> 4) * 16)) ^ ((row & 7) << 4);
        af[m] = *(const bf16x8*)(As + row * (BK * 2) + kb);
      }
#pragma unroll
      for (int n = 0; n < FN; ++n) {
        const int row = wc * WTN + n * 16 + (lane & 15);
        const int kb = (ks * 64 + ((lane >> 4) * 16)) ^ ((row & 7) << 4);
        bfr[n] = *(const bf16x8*)(Bs + row * (BK * 2) + kb);
      }
#pragma unroll
      for (int m = 0; m < FM; ++m)
#pragma unroll
        for (int n = 0; n < FN; ++n)
          acc[m][n] = __builtin_amdgcn_mfma_f32_16x16x32_bf16(
              af[m], bfr[n], acc[m][n], 0, 0, 0);
    }
  }

  // epilogue: C/D layout col = lane&15, row = (lane>>4)*4 + j  [m89/m91]
  const int cc = lane & 15;
  const int cr0 = (lane >> 4) * 4;
#pragma unroll
  for (int m = 0; m < FM; ++m) {
#pragma unroll
    for (int n = 0; n < FN; ++n) {
#pragma unroll
      for (int j = 0; j < 4; ++j) {
        const int grow = m0 + wr * WTM + m * 16 + cr0 + j;
        const int gcol = n0 + wc * WTN + n * 16 + cc;
        const float v = acc[m][n][j];
        if constexpr (EPI == EPI_BF16) {
          ((unsigned short*)Cp)[(size_t)grow * ldc + gcol] = f2bf(v);
        } else if constexpr (EPI == EPI_KE) {
          int ar = grow;
          if (arowmap) { ar = arowmap[grow]; if (ar < 0) ar = 0; }
          const float ksv = bf2f(aux[(size_t)ar * ldaux + gcol]);
          float r = ksv + 2.0f * v;      // LORA_SCALING = 2
          r = r > 0.f ? r : 0.f;
          ((unsigned short*)Cp)[(size_t)grow * ldc + gcol] = f2bf(r * r);
        } else {
          int t = grow;
          if (crowmap) t = crowmap[grow];
          if (t >= 0) {
            const float g = gate[t] * scale;
            float* o = (float*)Cp + (size_t)t * ldc + gcol;
            *o = initC ? (g * v) : (*o + g * v);
          }
        }
      }
    }
  }
}

// ---------------------------------------------------------------------------
extern "C" void kernel_launch(void* const* d_in, const int* in_sizes, int n_in,
                              void* d_out, int out_size, void* d_ws,
                              size_t ws_size, hipStream_t stream) {
  (void)in_sizes; (void)n_in; (void)out_size;
  const float* x      = (const float*)d_in[0];
  const float* x_prev = (const float*)d_in[1];
  const float* x_k    = (const float*)d_in[2];
  const float* Router = (const float*)d_in[3];
  const float* K_ref  = (const float*)d_in[4];
  const float* V_ref  = (const float*)d_in[5];
  const float* Ka     = (const float*)d_in[6];
  const float* Kb     = (const float*)d_in[7];
  const float* Va     = (const float*)d_in[8];
  const float* Vb     = (const float*)d_in[9];

  constexpr int Bb = 4, T = 2048, C = 2048, H = 8192, R = 64, E = 4;
  constexpr int M = Bb * T;  // 8192 tokens

  const size_t PAD = 255;
  auto rnd = [&](size_t b) { return (b + PAD) & ~PAD; };
  const size_t persist = rnd((size_t)H * C * 2) + rnd((size_t)C * H * 2)
                       + rnd((size_t)E * R * C * 2) + rnd((size_t)E * H * R * 2)
                       + rnd((size_t)E * R * H * 2) + rnd((size_t)E * C * R * 2);

  // largest chunk MC (pow2 multiple of 128, divides M) whose buffers fit
  int MC = 0;
  for (int cand = M; cand >= 128; cand >>= 1) {
    const int mb = cand / 128 + 4;            // m-blocks incl. worst-case pad
    const size_t per = rnd((size_t)cand * C * 2)               // h_c
                     + rnd((size_t)cand * E * R * 2)           // lora
                     + rnd((size_t)cand * H * 2)               // ksh
                     + rnd((size_t)mb * 128 * H * 2)           // k_e (compact)
                     + rnd((size_t)mb * 128 * R * 2)           // vat (compact)
                     + rnd((size_t)(32 + 2 * mb + 2 * mb * 128) * 4)  // tbl
                     + rnd((size_t)2 * cand * 4)               // etok
                     + rnd((size_t)2 * cand * 4);              // gate_tok
    if (persist + per <= ws_size) { MC = cand; break; }
  }
  if (MC == 0) return;
  const int MB = MC / 128 + 4;
  const int PR = MB * 128;

  char* ws = (char*)d_ws;
  size_t off = 0;
  auto alloc = [&](size_t bytes) -> char* {
    char* p = ws + off; off += rnd(bytes); return p;
  };
  unsigned short* Kt   = (unsigned short*)alloc((size_t)H * C * 2);
  unsigned short* Vt   = (unsigned short*)alloc((size_t)C * H * 2);
  unsigned short* KaB  = (unsigned short*)alloc((size_t)E * R * C * 2);
  unsigned short* KbB  = (unsigned short*)alloc((size_t)E * H * R * 2);
  unsigned short* VaB  = (unsigned short*)alloc((size_t)E * R * H * 2);
  unsigned short* VbB  = (unsigned short*)alloc((size_t)E * C * R * 2);
  unsigned short* h_c  = (unsigned short*)alloc((size_t)MC * C * 2);
  unsigned short* lora = (unsigned short*)alloc((size_t)MC * E * R * 2);
  unsigned short* ksh  = (unsigned short*)alloc((size_t)MC * H * 2);
  unsigned short* k_e  = (unsigned short*)alloc((size_t)PR * H * 2);
  unsigned short* vat  = (unsigned short*)alloc((size_t)PR * R * 2);
  int*            tbl  = (int*)alloc((size_t)(32 + 2 * MB + 2 * PR) * 4);
  int*            etok = (int*)alloc((size_t)2 * MC * 4);
  float*          gtok = (float*)alloc((size_t)2 * MC * 4);

  float* out    = (float*)d_out;
  float* x_last = out + (size_t)M * C;

  // ---- one-time: weights -> bf16 (K_ref/V_ref transposed to B^T) ----
  transpose_cast<<<dim3(H / 32, C / 32), dim3(32, 8), 0, stream>>>(K_ref, Kt, C, H);
  transpose_cast<<<dim3(C / 32, H / 32), dim3(32, 8), 0, stream>>>(V_ref, Vt, H, C);
  cast_bf16<<<(E * R * C / 4 + 255) / 256, 256, 0, stream>>>(Ka, KaB, E * R * C / 4);
  cast_bf16<<<(E * H * R / 4 + 255) / 256, 256, 0, stream>>>(Kb, KbB, E * H * R / 4);
  cast_bf16<<<(E * R * H / 4 + 255) / 256, 256, 0, stream>>>(Va, VaB, E * R * H / 4);
  cast_bf16<<<(E * C * R / 4 + 255) / 256, 256, 0, stream>>>(Vb, VbB, E * C * R / 4);
  xlast_kernel<<<Bb * C / 4 / 256, 256, 0, stream>>>(x, x_last);

  // ---- per-chunk pipeline ----
  for (int c0 = 0; c0 < M; c0 += MC) {
    prep_kernel<<<MC * C / 4 / 256, 256, 0, stream>>>(x, x_prev, x_k, h_c, c0);
    zero_hist<<<1, 64, 0, stream>>>(tbl);
    router_kernel<<<MC / 4, 256, 0, stream>>>(x, x_prev, x_k, Router, tbl,
                                              etok, gtok, MC, c0);
    seg_build<<<1, 128, 0, stream>>>(tbl, MB);
    scatter_build<<<(MC + 255) / 256, 256, 0, stream>>>(tbl, etok, MC, MB);

    // ksh = h @ K_ref   [MC x H], K=C (dense, shared across experts)
    gemm_bt<128, 4, EPI_BF16><<<dim3(H / 128, MC / 128), 256, 0, stream>>>(
        h_c, C, 0, Kt, C, 0, ksh, H, nullptr, 0, nullptr, 0.f, 0,
        nullptr, nullptr, nullptr, C);
    // lora = h @ KaAll^T  [MC x E*R], K=C (dense)
    gemm_bt<128, 4, EPI_BF16><<<dim3(E * R / 128, MC / 128), 256, 0, stream>>>(
        h_c, C, 0, KaB, C, 0, lora, E * R, nullptr, 0, nullptr, 0.f, 0,
        nullptr, nullptr, nullptr, C);

    for (int k = 0; k < 2; ++k) {
      const int* bt  = tbl + 32 + k * MB;
      const int* tok = tbl + 32 + 2 * MB + k * PR;
      const float* gk = gtok + k * MC;
      // k_e = relu(ksh[tok] + 2 * lora[tok, e*R:] @ Kb[e]^T)^2  [PR x H], K=R
      gemm_bt<128, 4, EPI_KE><<<dim3(H / 128, MB), 256, 0, stream>>>(
          lora, E * R, R, KbB, R, (long long)H * R, k_e, H, ksh, H,
          nullptr, 0.f, 0, bt, tok, nullptr, R);
      // vat = k_e @ Va[e]^T   [PR x R], K=H
      gemm_bt<64, 2, EPI_BF16><<<dim3(R / 64, MB), 128, 0, stream>>>(
          k_e, H, 0, VaB, H, (long long)R * H, vat, R, nullptr, 0,
          nullptr, 0.f, 0, bt, nullptr, nullptr, H);
      // out[tok] (+)= g * (k_e @ V_ref)   [PR x C], K=H ; init on slot 0
      gemm_bt<128, 4, EPI_GATE><<<dim3(C / 128, MB), 256, 0, stream>>>(
          k_e, H, 0, Vt, H, 0, out + (size_t)c0 * C, C, nullptr, 0,
          gk, 1.0f, (k == 0) ? 1 : 0, bt, nullptr, tok, H);
      // out[tok] += 2g * (vat @ Vb[e]^T)   [PR x C], K=R
      gemm_bt<128, 4, EPI_GATE><<<dim3(C / 128, MB), 256, 0, stream>>>(
          vat, R, 0, VbB, R, (long long)C * R, out + (size_t)c0 * C, C,
          nullptr, 0, gk, 2.0f, 0, bt, nullptr, tok, R);
    }
  }
}

// Round 7
// 2293.713 us; speedup vs baseline: 1.4864x; 1.1567x over previous
//
#include <hip/hip_runtime.h>

// ---------------------------------------------------------------------------
// RWKV-7 MoE FFN, MI355X (gfx950). bf16 MFMA + top-2 SPARSE expert dispatch.
// Slot-lists: slot0 = primary expert of each token, slot1 = secondary.
// vat fused into the out-GEMM (shared A, shared H-reduction, Va zero-padded
// to an extra n-block). XCD-bijective block swizzle (m204) on all GEMMs.
// Shapes fixed: B=4 T=2048 C=2048 H=8192 R=64 E=4, topk=2.
// ---------------------------------------------------------------------------

#define DEV_INLINE __device__ __forceinline__

typedef __attribute__((ext_vector_type(8))) short bf16x8;
typedef __attribute__((ext_vector_type(4))) float f32x4;

DEV_INLINE unsigned short f2bf(float f) {
  union { float f; unsigned int u; } v; v.f = f;
  unsigned int u = v.u;
  unsigned int r = (u + 0x7FFFu + ((u >> 16) & 1u)) >> 16;  // RTNE
  return (unsigned short)r;
}
DEV_INLINE float bf2f(unsigned short s) {
  union { unsigned int u; float f; } v; v.u = ((unsigned int)s) << 16;
  return v.f;
}

// tbl layout (ints): [0:8) hist[2][4], [8:16) fill[2][4], [16:26) base[2][5],
// [32:32+2*MB) blocktab[2][MB], [32+2*MB : ...) tok[2][MB*128]

// ---------------------------------------------------------------------------
__global__ __launch_bounds__(256) void prep_kernel(
    const float* __restrict__ x, const float* __restrict__ x_prev,
    const float* __restrict__ x_k, unsigned short* __restrict__ h, int n0) {
  const int idx = blockIdx.x * 256 + threadIdx.x;   // local float4 index
  const int c4 = idx & 511;                         // C/4 = 512
  const int gn = n0 + (idx >> 9);                   // global token
  const int t  = gn & 2047;                         // T = 2048
  const int b  = gn >> 11;
  const float4 cur = ((const float4*)x)[(size_t)gn * 512 + c4];
  const float4 prv = (t == 0) ? ((const float4*)x_prev)[(b << 9) + c4]
                              : ((const float4*)x)[(size_t)gn * 512 - 512 + c4];
  const float4 k = ((const float4*)x_k)[c4];
  float hx = cur.x + (prv.x - cur.x) * k.x;
  float hy = cur.y + (prv.y - cur.y) * k.y;
  float hz = cur.z + (prv.z - cur.z) * k.z;
  float hw = cur.w + (prv.w - cur.w) * k.w;
  uint2 o;
  o.x = (unsigned int)f2bf(hx) | ((unsigned int)f2bf(hy) << 16);
  o.y = (unsigned int)f2bf(hz) | ((unsigned int)f2bf(hw) << 16);
  ((uint2*)h)[idx] = o;
}

__global__ __launch_bounds__(256) void xlast_kernel(
    const float* __restrict__ x, float* __restrict__ x_last) {
  const int i = blockIdx.x * 256 + threadIdx.x;  // [0, 2048)
  const int b = i >> 9, c4 = i & 511;
  ((float4*)x_last)[i] =
      ((const float4*)x)[((size_t)b * 2048 + 2047) * 512 + c4];
}

__global__ __launch_bounds__(256) void transpose_cast(
    const float* __restrict__ in, unsigned short* __restrict__ outp,
    int rows, int cols) {
  __shared__ float tile[32][33];
  const int bx = blockIdx.x * 32, by = blockIdx.y * 32;
  const int tx = threadIdx.x, ty = threadIdx.y;
#pragma unroll
  for (int k = 0; k < 4; ++k)
    tile[ty + k * 8][tx] = in[(size_t)(by + ty + k * 8) * cols + bx + tx];
  __syncthreads();
#pragma unroll
  for (int k = 0; k < 4; ++k)
    outp[(size_t)(bx + ty + k * 8) * rows + by + tx] = f2bf(tile[tx][ty + k * 8]);
}

__global__ __launch_bounds__(256) void cast_bf16(
    const float* __restrict__ in, unsigned short* __restrict__ outp, int n4) {
  const int i = blockIdx.x * 256 + threadIdx.x;
  if (i >= n4) return;
  const float4 v = ((const float4*)in)[i];
  uint2 o;
  o.x = (unsigned int)f2bf(v.x) | ((unsigned int)f2bf(v.y) << 16);
  o.y = (unsigned int)f2bf(v.z) | ((unsigned int)f2bf(v.w) << 16);
  ((uint2*)outp)[i] = o;
}

// Va [E][64][H] f32 -> VaPad [E][128][H] bf16, rows 64..127 = 0
__global__ __launch_bounds__(256) void pad_cast_va(
    const float* __restrict__ in, unsigned short* __restrict__ outp) {
  const int i = blockIdx.x * 256 + threadIdx.x;  // uint2 (4 bf16) index
  const int H4 = 8192 / 4;
  const int e = i / (128 * H4);
  const int rem = i - e * 128 * H4;
  const int row = rem / H4, c4 = rem - row * H4;
  uint2 o;
  if (row < 64) {
    const float4 v = ((const float4*)in)[((size_t)e * 64 + row) * H4 + c4];
    o.x = (unsigned int)f2bf(v.x) | ((unsigned int)f2bf(v.y) << 16);
    o.y = (unsigned int)f2bf(v.z) | ((unsigned int)f2bf(v.w) << 16);
  } else {
    o.x = 0; o.y = 0;
  }
  ((uint2*)outp)[i] = o;
}

// ---------------------------------------------------------------------------
// router (f32 end-to-end from raw inputs): per token top-2 -> expert ids,
// gate values, and per-(slot,expert) histogram.
// ---------------------------------------------------------------------------
__global__ __launch_bounds__(256) void router_kernel(
    const float* __restrict__ x, const float* __restrict__ x_prev,
    const float* __restrict__ x_k, const float* __restrict__ Rt,
    int* __restrict__ tbl, int* __restrict__ etok,
    float* __restrict__ gate_tok, int MC, int n0) {
  const int lane = threadIdx.x & 63, wid = threadIdx.x >> 6;
  const int nl = blockIdx.x * 4 + wid;  // local token
  const int gn = n0 + nl;
  const int t = gn & 2047, b = gn >> 11;
  const float* cur = x + (size_t)gn * 2048;
  const float* prv = (t == 0) ? x_prev + (size_t)b * 2048 : cur - 2048;
  float hv[32];
#pragma unroll
  for (int j = 0; j < 32; ++j) {
    const int i = j * 64 + lane;
    const float xc = cur[i];
    hv[j] = xc + (prv[i] - xc) * x_k[i];
  }
  float s[4];
  s[0] = 0.f;
  for (int e = 1; e < 4; ++e) {
    const float* rrow = Rt + (size_t)(e - 1) * 2048;
    float a = 0.f;
#pragma unroll
    for (int j = 0; j < 32; ++j) a += hv[j] * rrow[j * 64 + lane];
#pragma unroll
    for (int d = 32; d >= 1; d >>= 1) a += __shfl_xor(a, d, 64);
    s[e] = a;
  }
  if (lane == 0) {
    int i1 = 0; float v1 = s[0];
    for (int e = 1; e < 4; ++e) if (s[e] > v1) { v1 = s[e]; i1 = e; }
    int i2 = -1; float v2 = -1e30f;
    for (int e = 0; e < 4; ++e) if (e != i1 && s[e] > v2) { v2 = s[e]; i2 = e; }
    const float ex = expf(v2 - v1);
    const float g1 = 1.f / (1.f + ex), g2 = ex / (1.f + ex);
    etok[nl] = i1;          etok[MC + nl] = i2;
    gate_tok[nl] = g1;      gate_tok[MC + nl] = g2;
    atomicAdd(&tbl[i1], 1); atomicAdd(&tbl[4 + i2], 1);
  }
}

__global__ void zero_hist(int* tbl) {
  if (threadIdx.x < 8) tbl[threadIdx.x] = 0;
}

// 1 block, 128 threads: bases (128-padded prefix), blocktab, tok=-1, fill=0
__global__ __launch_bounds__(128) void seg_build(int* __restrict__ tbl, int MB) {
  const int tid = threadIdx.x;
  __shared__ int sbase[2][5];
  if (tid == 0) {
    for (int k = 0; k < 2; ++k) {
      int b = 0; sbase[k][0] = 0;
      for (int e = 0; e < 4; ++e) {
        b += ((tbl[k * 4 + e] + 127) >> 7) << 7;
        sbase[k][e + 1] = b;
      }
      for (int e = 0; e < 5; ++e) tbl[16 + k * 5 + e] = sbase[k][e];
    }
    for (int i = 0; i < 8; ++i) tbl[8 + i] = 0;
  }
  __syncthreads();
  int* bt = tbl + 32;
  for (int i = tid; i < 2 * MB; i += 128) {
    const int k = i / MB, row = (i % MB) * 128;
    int e = -1;
    for (int q = 0; q < 4; ++q)
      if (row >= sbase[k][q] && row < sbase[k][q + 1]) e = q;
    bt[i] = e;
  }
  int* tok = tbl + 32 + 2 * MB;
  for (int i = tid; i < 2 * MB * 128; i += 128) tok[i] = -1;
}

__global__ __launch_bounds__(256) void scatter_build(
    int* __restrict__ tbl, const int* __restrict__ etok, int MC, int MB) {
  const int t = blockIdx.x * 256 + threadIdx.x;
  if (t >= MC) return;
  int* tok = tbl + 32 + 2 * MB;
#pragma unroll
  for (int k = 0; k < 2; ++k) {
    const int e = etok[k * MC + t];
    const int r = atomicAdd(&tbl[8 + k * 4 + e], 1);
    tok[k * MB * 128 + tbl[16 + k * 5 + e] + r] = t;
  }
}

// ---------------------------------------------------------------------------
// Generic B^T GEMM, 1D grid with XCD-bijective swizzle (m204), optional
// expert segmentation / row gather / scatter. 128 x 128 x BK=64 tile,
// mfma_f32_16x16x32_bf16, global_load_lds width-16, XOR-swizzled LDS.
// EPI_BF16: store bf16. EPI_KE: k_e = relu(aux[gather] + 2*acc)^2 bf16.
// EPI_GATEVAT: normal n-blocks: out[tok] (+)= gate*acc (f32);
//              if B2 != null, n-block nbx-1 uses B = B2 + e*128*ldb (VaPad)
//              and stores bf16 vat cols 0..63 instead.
// ---------------------------------------------------------------------------
enum { EPI_BF16 = 0, EPI_KE = 1, EPI_GATEVAT = 2 };

template <int EPI>
__global__ __launch_bounds__(256) void gemm_bt(
    const unsigned short* __restrict__ A, int lda, long long strideA,
    const unsigned short* __restrict__ B, int ldb, long long strideB,
    const unsigned short* __restrict__ B2,
    void* __restrict__ Cp, int ldc, unsigned short* __restrict__ vat,
    const unsigned short* __restrict__ aux, int ldaux,
    const float* __restrict__ gate, float scale, int initC,
    const int* __restrict__ blocktab, const int* __restrict__ arowmap,
    const int* __restrict__ crowmap, int K, int nbx) {
  constexpr int BM = 128, BN = 128, BK = 64;
  constexpr int WN = 2;
  constexpr int WTM = 64, WTN = 64;
  constexpr int FMr = WTM / 16, FNr = WTN / 16;   // 4 x 4 fragments
  constexpr int THREADS = 256;
  constexpr int ACH = BM * BK / 8;
  constexpr int BCH = BN * BK / 8;

  // --- XCD-bijective swizzle (m204), then decode 2D tile coords ---
  const int nwg = gridDim.x;
  const int wg = blockIdx.x;
  const int q = nwg >> 3, r = nwg & 7;
  const int xcd = wg & 7, loc = wg >> 3;
  const int swz = (xcd < r ? xcd * (q + 1) : r * (q + 1) + (xcd - r) * q) + loc;
  const int bx = swz % nbx;
  const int by = swz / nbx;

  int e = 0;
  if (blocktab) { e = blocktab[by]; if (e < 0) return; }

  __shared__ alignas(16) char smem[(BM + BN) * BK * 2];
  char* As = smem;
  char* Bs = smem + BM * BK * 2;

  const unsigned short* Ae = A + (size_t)e * strideA;
  const bool vatBlk =
      (EPI == EPI_GATEVAT) && (B2 != nullptr) && (bx == nbx - 1);
  const unsigned short* Be;
  int bn0;
  if (vatBlk) { Be = B2 + (size_t)e * 128 * ldb; bn0 = 0; }
  else        { Be = B + (size_t)e * strideB;    bn0 = bx * BN; }

  const int tid = threadIdx.x;
  const int lane = tid & 63;
  const int wid = tid >> 6;
  const int wr = wid / WN, wc = wid % WN;
  const int m0 = by * BM;

  // cache this thread's A-row gather targets (fixed across K)
  int arow[ACH / THREADS];
#pragma unroll
  for (int i = 0; i < ACH / THREADS; ++i) {
    const int row = (i * THREADS + tid) >> 3;
    int rr = m0 + row;
    if (arowmap) { rr = arowmap[rr]; if (rr < 0) rr = 0; }
    arow[i] = rr;
  }

  f32x4 acc[FMr][FNr] = {};

  for (int kt = 0; kt < K; kt += BK) {
    __syncthreads();
#pragma unroll
    for (int i = 0; i < ACH / THREADS; ++i) {
      const int qq = i * THREADS + tid;
      const int row = qq >> 3, w = qq & 7;
      const int g = w ^ (row & 7);
      const unsigned short* src = Ae + (size_t)arow[i] * lda + kt + g * 8;
      __builtin_amdgcn_global_load_lds(
          (const __attribute__((address_space(1))) void*)src,
          (__attribute__((address_space(3))) void*)(As + qq * 16), 16, 0, 0);
    }
#pragma unroll
    for (int i = 0; i < BCH / THREADS; ++i) {
      const int qq = i * THREADS + tid;
      const int row = qq >> 3, w = qq & 7;
      const int g = w ^ (row & 7);
      const unsigned short* src = Be + (size_t)(bn0 + row) * ldb + kt + g * 8;
      __builtin_amdgcn_global_load_lds(
          (const __attribute__((address_space(1))) void*)src,
          (__attribute__((address_space(3))) void*)(Bs + qq * 16), 16, 0, 0);
    }
    asm volatile("s_waitcnt vmcnt(0)" ::: "memory");
    __syncthreads();

#pragma unroll
    for (int ks = 0; ks < BK / 32; ++ks) {
      bf16x8 af[FMr], bfr[FNr];
#pragma unroll
      for (int m = 0; m < FMr; ++m) {
        const int row = wr * WTM + m * 16 + (lane & 15);
        const int kb = (ks * 64 + ((lane >> 4) * 16)) ^ ((row & 7) << 4);
        af[m] = *(const bf16x8*)(As + row * (BK * 2) + kb);
      }
#pragma unroll
      for (int n = 0; n < FNr; ++n) {
        const int row = wc * WTN + n * 16 + (lane & 15);
        const int kb = (ks * 64 + ((lane >> 4) * 16)) ^ ((row & 7) << 4);
        bfr[n] = *(const bf16x8*)(Bs + row * (BK * 2) + kb);
      }
#pragma unroll
      for (int m = 0; m < FMr; ++m)
#pragma unroll
        for (int n = 0; n < FNr; ++n)
          acc[m][n] = __builtin_amdgcn_mfma_f32_16x16x32_bf16(
              af[m], bfr[n], acc[m][n], 0, 0, 0);
    }
  }

  // epilogue: C/D layout col = lane&15, row = (lane>>4)*4 + j  [m89/m91]
  const int cc = lane & 15;
  const int cr0 = (lane >> 4) * 4;
#pragma unroll
  for (int m = 0; m < FMr; ++m) {
#pragma unroll
    for (int n = 0; n < FNr; ++n) {
#pragma unroll
      for (int j = 0; j < 4; ++j) {
        const int grow = m0 + wr * WTM + m * 16 + cr0 + j;
        const int lcol = wc * WTN + n * 16 + cc;     // 0..127 within tile
        const float v = acc[m][n][j];
        if constexpr (EPI == EPI_BF16) {
          ((unsigned short*)Cp)[(size_t)grow * ldc + bx * BN + lcol] = f2bf(v);
        } else if constexpr (EPI == EPI_KE) {
          int ar = grow;
          if (arowmap) { ar = arowmap[grow]; if (ar < 0) ar = 0; }
          const float ksv = bf2f(aux[(size_t)ar * ldaux + bx * BN + lcol]);
          float rr = ksv + 2.0f * v;     // LORA_SCALING = 2
          rr = rr > 0.f ? rr : 0.f;
          ((unsigned short*)Cp)[(size_t)grow * ldc + bx * BN + lcol] =
              f2bf(rr * rr);
        } else {
          if (vatBlk) {
            if (lcol < 64) vat[(size_t)grow * 64 + lcol] = f2bf(v);
          } else {
            int t = grow;
            if (crowmap) t = crowmap[grow];
            if (t >= 0) {
              const float g = gate[t] * scale;
              float* o = (float*)Cp + (size_t)t * ldc + bx * BN + lcol;
              *o = initC ? (g * v) : (*o + g * v);
            }
          }
        }
      }
    }
  }
}

// ---------------------------------------------------------------------------
extern "C" void kernel_launch(void* const* d_in, const int* in_sizes, int n_in,
                              void* d_out, int out_size, void* d_ws,
                              size_t ws_size, hipStream_t stream) {
  (void)in_sizes; (void)n_in; (void)out_size;
  const float* x      = (const float*)d_in[0];
  const float* x_prev = (const float*)d_in[1];
  const float* x_k    = (const float*)d_in[2];
  const float* Router = (const float*)d_in[3];
  const float* K_ref  = (const float*)d_in[4];
  const float* V_ref  = (const float*)d_in[5];
  const float* Ka     = (const float*)d_in[6];
  const float* Kb     = (const float*)d_in[7];
  const float* Va     = (const float*)d_in[8];
  const float* Vb     = (const float*)d_in[9];

  constexpr int Bb = 4, T = 2048, C = 2048, H = 8192, R = 64, E = 4;
  constexpr int M = Bb * T;  // 8192 tokens

  const size_t PAD = 255;
  auto rnd = [&](size_t b) { return (b + PAD) & ~PAD; };
  const size_t persist = rnd((size_t)H * C * 2) + rnd((size_t)C * H * 2)
                       + rnd((size_t)E * R * C * 2) + rnd((size_t)E * H * R * 2)
                       + rnd((size_t)E * 128 * H * 2)   // VaPad
                       + rnd((size_t)E * C * R * 2);

  // largest chunk MC (pow2 multiple of 128, divides M) whose buffers fit
  int MC = 0;
  for (int cand = M; cand >= 128; cand >>= 1) {
    const int mb = cand / 128 + 4;            // m-blocks incl. worst-case pad
    const size_t per = rnd((size_t)cand * C * 2)               // h_c
                     + rnd((size_t)cand * E * R * 2)           // lora
                     + rnd((size_t)cand * H * 2)               // ksh
                     + rnd((size_t)mb * 128 * H * 2)           // k_e (compact)
                     + rnd((size_t)mb * 128 * 64 * 2)          // vat (compact)
                     + rnd((size_t)(32 + 2 * mb + 2 * mb * 128) * 4)  // tbl
                     + rnd((size_t)2 * cand * 4)               // etok
                     + rnd((size_t)2 * cand * 4);              // gate_tok
    if (persist + per <= ws_size) { MC = cand; break; }
  }
  if (MC == 0) return;
  const int MB = MC / 128 + 4;
  const int PR = MB * 128;

  char* ws = (char*)d_ws;
  size_t off = 0;
  auto alloc = [&](size_t bytes) -> char* {
    char* p = ws + off; off += rnd(bytes); return p;
  };
  unsigned short* Kt    = (unsigned short*)alloc((size_t)H * C * 2);
  unsigned short* Vt    = (unsigned short*)alloc((size_t)C * H * 2);
  unsigned short* KaB   = (unsigned short*)alloc((size_t)E * R * C * 2);
  unsigned short* KbB   = (unsigned short*)alloc((size_t)E * H * R * 2);
  unsigned short* VaPad = (unsigned short*)alloc((size_t)E * 128 * H * 2);
  unsigned short* VbB   = (unsigned short*)alloc((size_t)E * C * R * 2);
  unsigned short* h_c   = (unsigned short*)alloc((size_t)MC * C * 2);
  unsigned short* lora  = (unsigned short*)alloc((size_t)MC * E * R * 2);
  unsigned short* ksh   = (unsigned short*)alloc((size_t)MC * H * 2);
  unsigned short* k_e   = (unsigned short*)alloc((size_t)PR * H * 2);
  unsigned short* vat   = (unsigned short*)alloc((size_t)PR * 64 * 2);
  int*            tbl   = (int*)alloc((size_t)(32 + 2 * MB + 2 * PR) * 4);
  int*            etok  = (int*)alloc((size_t)2 * MC * 4);
  float*          gtok  = (float*)alloc((size_t)2 * MC * 4);

  float* out    = (float*)d_out;
  float* x_last = out + (size_t)M * C;

  // ---- one-time: weights -> bf16 ----
  transpose_cast<<<dim3(H / 32, C / 32), dim3(32, 8), 0, stream>>>(K_ref, Kt, C, H);
  transpose_cast<<<dim3(C / 32, H / 32), dim3(32, 8), 0, stream>>>(V_ref, Vt, H, C);
  cast_bf16<<<(E * R * C / 4 + 255) / 256, 256, 0, stream>>>(Ka, KaB, E * R * C / 4);
  cast_bf16<<<(E * H * R / 4 + 255) / 256, 256, 0, stream>>>(Kb, KbB, E * H * R / 4);
  pad_cast_va<<<E * 128 * (H / 4) / 256, 256, 0, stream>>>(Va, VaPad);
  cast_bf16<<<(E * C * R / 4 + 255) / 256, 256, 0, stream>>>(Vb, VbB, E * C * R / 4);
  xlast_kernel<<<Bb * C / 4 / 256, 256, 0, stream>>>(x, x_last);

  // ---- per-chunk pipeline ----
  for (int c0 = 0; c0 < M; c0 += MC) {
    prep_kernel<<<MC * C / 4 / 256, 256, 0, stream>>>(x, x_prev, x_k, h_c, c0);
    zero_hist<<<1, 64, 0, stream>>>(tbl);
    router_kernel<<<MC / 4, 256, 0, stream>>>(x, x_prev, x_k, Router, tbl,
                                              etok, gtok, MC, c0);
    seg_build<<<1, 128, 0, stream>>>(tbl, MB);
    scatter_build<<<(MC + 255) / 256, 256, 0, stream>>>(tbl, etok, MC, MB);

    // ksh = h @ K_ref   [MC x H], K=C (dense, shared across experts)
    gemm_bt<EPI_BF16><<<(H / 128) * (MC / 128), 256, 0, stream>>>(
        h_c, C, 0, Kt, C, 0, nullptr, ksh, H, nullptr, nullptr, 0,
        nullptr, 0.f, 0, nullptr, nullptr, nullptr, C, H / 128);
    // lora = h @ KaAll^T  [MC x E*R], K=C (dense)
    gemm_bt<EPI_BF16><<<(E * R / 128) * (MC / 128), 256, 0, stream>>>(
        h_c, C, 0, KaB, C, 0, nullptr, lora, E * R, nullptr, nullptr, 0,
        nullptr, 0.f, 0, nullptr, nullptr, nullptr, C, E * R / 128);

    for (int k = 0; k < 2; ++k) {
      const int* bt  = tbl + 32 + k * MB;
      const int* tok = tbl + 32 + 2 * MB + k * PR;
      const float* gk = gtok + k * MC;
      // k_e = relu(ksh[tok] + 2 * lora[tok, e*R:] @ Kb[e]^T)^2  [PR x H], K=R
      gemm_bt<EPI_KE><<<(H / 128) * MB, 256, 0, stream>>>(
          lora, E * R, R, KbB, R, (long long)H * R, nullptr, k_e, H, nullptr,
          ksh, H, nullptr, 0.f, 0, bt, tok, nullptr, R, H / 128);
      // fused: out[tok] (+)= g*(k_e @ V_ref), vat = k_e @ Va[e]^T
      //   [PR x (C + vat block)], K=H ; init out on slot 0
      gemm_bt<EPI_GATEVAT><<<(C / 128 + 1) * MB, 256, 0, stream>>>(
          k_e, H, 0, Vt, H, 0, VaPad, out + (size_t)c0 * C, C, vat,
          nullptr, 0, gk, 1.0f, (k == 0) ? 1 : 0, bt, nullptr, tok, H,
          C / 128 + 1);
      // out[tok] += 2g * (vat @ Vb[e]^T)   [PR x C], K=R  (no vat block)
      gemm_bt<EPI_GATEVAT><<<(C / 128) * MB, 256, 0, stream>>>(
          vat, 64, 0, VbB, R, (long long)C * R, nullptr,
          out + (size_t)c0 * C, C, nullptr, nullptr, 0, gk, 2.0f, 0,
          bt, nullptr, tok, R, C / 128);
    }
  }
}